// Round 10
// baseline (5113.778 us; speedup 1.0000x reference)
//
#include <hip/hip_runtime.h>
#include <hip/hip_bf16.h>
#include <stdint.h>

// SubLSTM T=1024, B=64, H=512, GATE=3H, L=2 — fused 2-layer pipelined,
// round 10: r9 + vmcnt hygiene. vmem retirement is IN-ORDER per wave, so any
// s_waitcnt for the sweep also drains every older op. r9 issued xb HBM loads
// and out-store flushes 0.25us before the first tag check -> the check ate an
// HBM round-trip every round. Now: phase A issues ONLY sweep loads; xb loads
// are issued at C-end (vmcnt empty) and live in registers for one full round
// (~1.3us of cover >= HBM latency) before being written to LDS at the next
// C-end; out-stores flush at C-end too (>=1.2us before the next check).
//
// Topology/protocol unchanged from r9: 8 groups x 8 rows; 32 blocks/group
// (16 h-cols, both layers; weights in regs). Round i: L0 t=i, L1 t=i-1.
// Exchange u64 = (tag32<<32)|(2xbf16), relaxed agent atomics (data IS the
// flag; single-copy atomic). Ring depth 4; skew <= 1 by sweep coupling;
// cross-replay stale accepts are bit-identical; 0xAA never matches a tag.

#define TSTEPS 1024
#define BATCH  64
#define HID    512
#define GATE   1536
#define GROWS  8
#define NT     256
#define NBLOCKS 256

typedef unsigned long long u64;
typedef __attribute__((ext_vector_type(8))) short short8;
typedef __attribute__((ext_vector_type(4))) short short4v;
typedef __attribute__((ext_vector_type(4))) float floatx4;

__device__ __forceinline__ float sigmoidf_(float x) { return 1.0f / (1.0f + __expf(-x)); }

__device__ __forceinline__ unsigned short f2bf(float x) {
    union { float f; unsigned u; } v; v.f = x;
    unsigned r = v.u + 0x7FFFu + ((v.u >> 16) & 1u);   // RNE
    return (unsigned short)(r >> 16);
}

__device__ __forceinline__ short8 load_frag(const float* p) {
    floatx4 a = *(const floatx4*)p;
    floatx4 b = *(const floatx4*)(p + 4);
    short8 r;
#pragma unroll
    for (int j = 0; j < 4; ++j) { r[j] = (short)f2bf(a[j]); r[j+4] = (short)f2bf(b[j]); }
    return r;
}

__device__ __forceinline__ u64 ring_ld(const u64* p) {
    return __hip_atomic_load(p, __ATOMIC_RELAXED, __HIP_MEMORY_SCOPE_AGENT);
}
__device__ __forceinline__ void ring_st(u64* p, u64 v) {
    __hip_atomic_store(p, v, __ATOMIC_RELAXED, __HIP_MEMORY_SCOPE_AGENT);
}

// ---- preamble: x f32 -> bf16 ----
__global__ __launch_bounds__(256) void xconvert(const float* __restrict__ x,
                                                unsigned short* __restrict__ xb) {
    const size_t i = ((size_t)blockIdx.x*256 + threadIdx.x) * 8;
    floatx4 a = *(const floatx4*)(x + i);
    floatx4 b = *(const floatx4*)(x + i + 4);
    short8 p;
#pragma unroll
    for (int j = 0; j < 4; ++j) { p[j] = (short)f2bf(a[j]); p[j+4] = (short)f2bf(b[j]); }
    *(short8*)(xb + i) = p;
}

__global__ __launch_bounds__(NT, 1) void sublstm_fused(
    const unsigned short* __restrict__ xb,
    const float* __restrict__ W,
    const float* __restrict__ R,
    const float* __restrict__ bi,
    const float* __restrict__ bh,
    const float* __restrict__ fw,
    const float* __restrict__ h0,
    const float* __restrict__ c0,
    u64* __restrict__ ring,        // [lyr 2][slot 4][grp 8][blk 32][row 8][unit 8]
    float* __restrict__ out)
{
    const int tid  = threadIdx.x;
    const int lane = tid & 63;
    const int wid  = tid >> 6;            // 0,1,2 = i/o/z gate waves; 3 = helper
    const int bid  = blockIdx.x;
    const int g    = bid & 7;             // batch group
    const int bidx = bid >> 3;            // 0..31: 16-col slice
    const int col0 = bidx << 4;

    __shared__ __align__(16) unsigned short x_tile[2][16][520];
    __shared__ __align__(16) unsigned short hA[16][520];    // h0_{i-1}
    __shared__ __align__(16) unsigned short hB[16][520];    // h1_{i-2}
    __shared__ float proj[2][3][16][17];

    for (int i = tid; i < 2*16*520; i += NT) ((unsigned short*)x_tile)[i] = 0;
    for (int i = tid; i < 16*520; i += NT) {
        ((unsigned short*)hA)[i] = 0;
        ((unsigned short*)hB)[i] = 0;
    }
    __syncthreads();   // zero-init visible before staging

    const int lrow = lane & 15;
    const int lk   = (lane >> 4) << 3;

    // ---- weights for both layers in regs (gate waves only) ----
    short8 wf0[16], rf0[16], wf1[16], rf1[16];
    float bias0 = 0.f, bias1 = 0.f;
    if (wid < 3) {
        const int wrow = wid*HID + col0 + lrow;
#pragma unroll
        for (int kc = 0; kc < 16; ++kc) {
            wf0[kc] = load_frag(W + (size_t)wrow*HID + kc*32 + lk);
            rf0[kc] = load_frag(R + (size_t)wrow*HID + kc*32 + lk);
            wf1[kc] = load_frag(W + ((size_t)GATE + wrow)*HID + kc*32 + lk);
            rf1[kc] = load_frag(R + ((size_t)GATE + wrow)*HID + kc*32 + lk);
        }
        bias0 = bi[wrow] + bh[wrow];
        bias1 = bi[GATE + wrow] + bh[GATE + wrow];
    }

    // ---- state: 1 cell per thread ----
    const int lyr  = tid >> 7;            // waves 0,1 -> L0; waves 2,3 -> L1
    const int srow = (tid >> 4) & 7;
    const int scol = tid & 15;
    const float fgv = sigmoidf_(fw[(size_t)lyr*HID + col0 + scol]);
    float creg = c0[((size_t)lyr*BATCH + g*GROWS + srow)*HID + col0 + scol];

    // ---- prologue: stage x_0, h0 tiles; issue xr <- step 1 ----
    {
        const unsigned short* xp = xb + (size_t)g*GROWS*HID;
        for (int w = tid; w < GROWS*HID/8; w += NT) {
            const int r = w >> 6, c8 = (w & 63) << 3;
            *(short8*)(&x_tile[0][r][c8]) = *(const short8*)(xp + (size_t)r*HID + c8);
        }
        const float* hp0 = h0 + (size_t)g*GROWS*HID;
        const float* hp1 = h0 + ((size_t)BATCH + g*GROWS)*HID;
        for (int w = tid; w < GROWS*HID/4; w += NT) {
            const int r = w >> 7, c4 = (w & 127) << 2;
            floatx4 va_ = *(const floatx4*)(hp0 + (size_t)r*HID + c4);
            floatx4 vb_ = *(const floatx4*)(hp1 + (size_t)r*HID + c4);
            short4v pa, pb;
#pragma unroll
            for (int j = 0; j < 4; ++j) { pa[j] = (short)f2bf(va_[j]); pb[j] = (short)f2bf(vb_[j]); }
            *(short4v*)(&hA[r][c4]) = pa;
            *(short4v*)(&hB[r][c4]) = pb;
        }
    }
    short8 xr0, xr1;                      // one-round-resident x prefetch regs
    {
        const unsigned short* xp = xb + (size_t)1*BATCH*HID + (size_t)g*GROWS*HID;
        xr0 = *(const short8*)(xp + (size_t)(tid >> 6)*HID + ((tid & 63) << 3));
        const int w1 = tid + 256;
        xr1 = *(const short8*)(xp + (size_t)(w1 >> 6)*HID + ((w1 & 63) << 3));
    }
    __syncthreads();

    int budget = 1 << 22;
    int pend_t = -1;                // deferred out-store (prev round's h,c)
    float pend_h = 0.f, pend_c = 0.f;

    for (int i = 0; i <= TSTEPS; ++i) {
        // ---- A: issue ONLY the sweep loads (clean vmcnt for the check) ----
        const int kmax = (i >= 2) ? 16 : ((i >= 1) ? 8 : 0);
        const u64* rb0 = ring + ((size_t)((i - 1) & 3)*8 + g)*2048;        // h0_{i-1}
        const u64* rb1 = ring + ((size_t)(4 + ((i - 2) & 3))*8 + g)*2048;  // h1_{i-2}
        u64 va[16];
#pragma unroll
        for (int k = 0; k < 16; ++k)
            if (k < kmax)
                va[k] = ring_ld((k < 8) ? (rb0 + tid + (k << 8))
                                        : (rb1 + tid + ((k - 8) << 8)));
        __builtin_amdgcn_sched_barrier(0);   // sweep issue stays above MFMAs

        // ---- B: exchange-independent chain a0a = x_i @ W0 ----
        floatx4 a0a = {0,0,0,0};
        if (wid < 3 && i < TSTEPS) {
            const int xq = i & 1;
#pragma unroll
            for (int kc = 0; kc < 16; ++kc) {
                short8 afx = *(const short8*)(&x_tile[xq][lrow][kc*32 + lk]);
                a0a = __builtin_amdgcn_mfma_f32_16x16x32_bf16(afx, wf0[kc], a0a, 0, 0, 0);
            }
        }
        __builtin_amdgcn_sched_barrier(0);   // check stays below the MFMAs

        // ---- C: tag check + batched conditional retries + stash ----
        if (kmax) {
            const unsigned wantA = (unsigned)i;         // h0_{i-1} tag
            const unsigned wantB = (unsigned)(i - 1);   // h1_{i-2} tag
            unsigned stale = 0;
#pragma unroll
            for (int k = 0; k < 16; ++k)
                if (k < kmax)
                    if ((unsigned)(va[k] >> 32) != ((k < 8) ? wantA : wantB))
                        stale |= (1u << k);
            while (__any((int)(stale != 0)) && budget > 0) {
#pragma unroll
                for (int k = 0; k < 16; ++k)
                    if (k < kmax && (stale & (1u << k)))
                        va[k] = ring_ld((k < 8) ? (rb0 + tid + (k << 8))
                                                : (rb1 + tid + ((k - 8) << 8)));
#pragma unroll
                for (int k = 0; k < 16; ++k)
                    if (k < kmax && (stale & (1u << k)))
                        if ((unsigned)(va[k] >> 32) == ((k < 8) ? wantA : wantB))
                            stale &= ~(1u << k);
                --budget;
            }
#pragma unroll
            for (int k = 0; k < 16; ++k) {
                if (k < kmax) {
                    const int w = tid + ((k & 7) << 8);    // 0..2047 within layer
                    const int b = w >> 6, r = (w >> 3) & 7, u = w & 7;
                    unsigned* dst = (k < 8)
                        ? (unsigned*)(&hA[r][b*16 + u*2])
                        : (unsigned*)(&hB[r][b*16 + u*2]);
                    *dst = (unsigned)va[k];
                }
            }
        }

        // ---- C-end: xr -> LDS (free wait), re-issue xr, flush out-stores ----
        if (i + 1 < TSTEPS) {   // xr holds step i+1 (loaded one round ago)
            const int xq = (i + 1) & 1;
            *(short8*)(&x_tile[xq][tid >> 6][(tid & 63) << 3]) = xr0;
            const int w1 = tid + 256;
            *(short8*)(&x_tile[xq][w1 >> 6][(w1 & 63) << 3]) = xr1;
        }
        if (i + 2 < TSTEPS) {   // issue step i+2; drains under D/E/A/B (~1.3us)
            const unsigned short* xp = xb + ((size_t)(i + 2)*BATCH + g*GROWS)*HID;
            xr0 = *(const short8*)(xp + (size_t)(tid >> 6)*HID + ((tid & 63) << 3));
            const int w1 = tid + 256;
            xr1 = *(const short8*)(xp + (size_t)(w1 >> 6)*HID + ((w1 & 63) << 3));
        }
        if (pend_t >= 0) {      // >=1.2us ahead of the next tag check
            if (lyr == 1)
                out[((size_t)pend_t*BATCH + g*GROWS + srow)*HID + col0 + scol] = pend_h;
            if (pend_t == TSTEPS - 1) {
                const size_t fo = (size_t)TSTEPS*BATCH*HID
                                + ((size_t)lyr*BATCH + g*GROWS + srow)*HID + col0 + scol;
                out[fo] = pend_h;                          // h_f
                out[fo + (size_t)2*BATCH*HID] = pend_c;    // c_f
            }
            pend_t = -1;
        }
        __syncthreads();   // B_mid: stash + x_tile visible before h-MFMAs

        // ---- D: h-dependent chains (3 independent) + sigmoid -> proj ----
        if (wid < 3) {
            floatx4 a0b = {0,0,0,0}, a1a = {0,0,0,0}, a1b = {0,0,0,0};
#pragma unroll
            for (int kc = 0; kc < 16; ++kc) {
                short8 afh = *(const short8*)(&hA[lrow][kc*32 + lk]);
                if (i < TSTEPS)
                    a0b = __builtin_amdgcn_mfma_f32_16x16x32_bf16(afh, rf0[kc], a0b, 0, 0, 0);
                if (i >= 1) {
                    short8 afb = *(const short8*)(&hB[lrow][kc*32 + lk]);
                    a1a = __builtin_amdgcn_mfma_f32_16x16x32_bf16(afh, wf1[kc], a1a, 0, 0, 0);
                    a1b = __builtin_amdgcn_mfma_f32_16x16x32_bf16(afb, rf1[kc], a1b, 0, 0, 0);
                }
            }
            const int erow0 = (lane >> 4) << 2, ecol = lrow;
#pragma unroll
            for (int q = 0; q < 4; ++q) {
                proj[0][wid][erow0 + q][ecol] = sigmoidf_(a0a[q] + a0b[q] + bias0);
                proj[1][wid][erow0 + q][ecol] = sigmoidf_(a1a[q] + a1b[q] + bias1);
            }
        }
        __syncthreads();   // B_proj

        // ---- E: state update + in-band publish; out stores deferred ----
        const int t = i - lyr;
        const bool act = lyr ? (i >= 1) : (i < TSTEPS);
        if (act) {
            const float ig = proj[lyr][0][srow][scol];
            const float og = proj[lyr][1][srow][scol];
            const float zz = proj[lyr][2][srow][scol];
            const float c_ = creg*fgv + zz - ig;
            creg = c_;
            const float h_ = sigmoidf_(c_) - og;
            if (i < TSTEPS) {
                const unsigned hu = __float_as_uint(h_);
                const unsigned pu = (unsigned)__builtin_amdgcn_ds_swizzle((int)hu, 0x041F);
                unsigned pay;
                asm volatile("v_cvt_pk_bf16_f32 %0, %1, %2"
                             : "=v"(pay) : "v"(h_), "v"(__uint_as_float(pu)));
                if (!(scol & 1)) {
                    const size_t off = ((((size_t)lyr*4 + (t & 3))*8 + g)*32 + bidx)*64
                                     + srow*8 + (scol >> 1);
                    ring_st(ring + off, (u64)pay | ((u64)(unsigned)(t + 1) << 32));
                }
            }
            pend_t = t; pend_h = h_; pend_c = c_;
        }
    }

    // ---- post-loop: flush the last deferred stores ----
    if (pend_t >= 0) {
        if (lyr == 1)
            out[((size_t)pend_t*BATCH + g*GROWS + srow)*HID + col0 + scol] = pend_h;
        if (pend_t == TSTEPS - 1) {
            const size_t fo = (size_t)TSTEPS*BATCH*HID
                            + ((size_t)lyr*BATCH + g*GROWS + srow)*HID + col0 + scol;
            out[fo] = pend_h;
            out[fo + (size_t)2*BATCH*HID] = pend_c;
        }
    }
}

extern "C" void kernel_launch(void* const* d_in, const int* in_sizes, int n_in,
                              void* d_out, int out_size, void* d_ws, size_t ws_size,
                              hipStream_t stream)
{
    (void)in_sizes; (void)n_in; (void)out_size; (void)ws_size;
    const float* x  = (const float*)d_in[0];
    const float* h0 = (const float*)d_in[1];
    const float* c0 = (const float*)d_in[2];
    const float* W  = (const float*)d_in[3];
    const float* R  = (const float*)d_in[4];
    const float* bi = (const float*)d_in[5];
    const float* bh = (const float*)d_in[6];
    const float* fw = (const float*)d_in[7];
    float* out = (float*)d_out;

    u64* ring = (u64*)d_ws;                                             // 1 MB
    unsigned short* xbuf = (unsigned short*)((char*)d_ws + (2u << 20)); // 64 MB

    hipMemsetAsync(d_ws, 0, (size_t)2*4*8*2048*8, stream);  // hygiene

    xconvert<<<dim3(TSTEPS*BATCH*HID/(256*8)), dim3(256), 0, stream>>>(x, xbuf);

    sublstm_fused<<<dim3(NBLOCKS), dim3(NT), 0, stream>>>(
        xbuf, W, R, bi, bh, fw, h0, c0, ring, out);
}

// Round 11
// 3467.462 us; speedup vs baseline: 1.4748x; 1.4748x over previous
//
#include <hip/hip_runtime.h>
#include <hip/hip_bf16.h>
#include <stdint.h>

// SubLSTM T=1024, B=64, H=512, GATE=3H, L=2 — fused 2-layer pipelined,
// round 11: staggered two-phase rounds. Each round = L0 half + L1 half with
// publishes offset half a round from their consumption:
//   C0 (consume h0_{i-1}, publ. mid-round i-1)  -> B1 -> L0 MFMAs+proj -> B2
//   -> issue va1 sweep -> E0 (flush outs; L0 update+publish h0_i)
//   -> a1a = hA@W1 (flight cover) -> C1 (consume h1_{i-2}, publ. round i-1)
//   -> B3 -> L1 a1b+proj -> B4 -> issue va0 sweep + x prefetch
//   -> E1 (L1 update+publish h1_{i-1}).
// In-order vmcnt discipline: every sweep is issued BEFORE the same-phase
// publish stores (older loads aren't gated by younger stores); each publish's
// ack drains during the other half's compute, never under a tag check.
// Protocol: u64 = (tag32<<32)|(2xbf16), relaxed agent atomics (data IS the
// flag). Ring depth 4; lock-step bounds skew; cross-replay stale accepts are
// bit-identical; 0xAA poison never matches a wanted tag. s_sleep(1) pacing on
// retry passes >=2 damps LLC congestion.

#define TSTEPS 1024
#define BATCH  64
#define HID    512
#define GATE   1536
#define GROWS  8
#define NT     256
#define NBLOCKS 256

typedef unsigned long long u64;
typedef __attribute__((ext_vector_type(8))) short short8;
typedef __attribute__((ext_vector_type(4))) short short4v;
typedef __attribute__((ext_vector_type(4))) float floatx4;

__device__ __forceinline__ float sigmoidf_(float x) { return 1.0f / (1.0f + __expf(-x)); }

__device__ __forceinline__ unsigned short f2bf(float x) {
    union { float f; unsigned u; } v; v.f = x;
    unsigned r = v.u + 0x7FFFu + ((v.u >> 16) & 1u);   // RNE
    return (unsigned short)(r >> 16);
}

__device__ __forceinline__ short8 load_frag(const float* p) {
    floatx4 a = *(const floatx4*)p;
    floatx4 b = *(const floatx4*)(p + 4);
    short8 r;
#pragma unroll
    for (int j = 0; j < 4; ++j) { r[j] = (short)f2bf(a[j]); r[j+4] = (short)f2bf(b[j]); }
    return r;
}

__device__ __forceinline__ u64 ring_ld(const u64* p) {
    return __hip_atomic_load(p, __ATOMIC_RELAXED, __HIP_MEMORY_SCOPE_AGENT);
}
__device__ __forceinline__ void ring_st(u64* p, u64 v) {
    __hip_atomic_store(p, v, __ATOMIC_RELAXED, __HIP_MEMORY_SCOPE_AGENT);
}

// ---- preamble: x f32 -> bf16 ----
__global__ __launch_bounds__(256) void xconvert(const float* __restrict__ x,
                                                unsigned short* __restrict__ xb) {
    const size_t i = ((size_t)blockIdx.x*256 + threadIdx.x) * 8;
    floatx4 a = *(const floatx4*)(x + i);
    floatx4 b = *(const floatx4*)(x + i + 4);
    short8 p;
#pragma unroll
    for (int j = 0; j < 4; ++j) { p[j] = (short)f2bf(a[j]); p[j+4] = (short)f2bf(b[j]); }
    *(short8*)(xb + i) = p;
}

__global__ __launch_bounds__(NT, 1) void sublstm_fused(
    const unsigned short* __restrict__ xb,
    const float* __restrict__ W,
    const float* __restrict__ R,
    const float* __restrict__ bi,
    const float* __restrict__ bh,
    const float* __restrict__ fw,
    const float* __restrict__ h0,
    const float* __restrict__ c0,
    u64* __restrict__ ring,        // [lyr 2][slot 4][grp 8][blk 32][row 8][unit 8]
    float* __restrict__ out)
{
    const int tid  = threadIdx.x;
    const int lane = tid & 63;
    const int wid  = tid >> 6;            // 0,1,2 = i/o/z gate waves; 3 = helper
    const int bid  = blockIdx.x;
    const int g    = bid & 7;             // batch group
    const int bidx = bid >> 3;            // 0..31: 16-col slice
    const int col0 = bidx << 4;

    __shared__ __align__(16) unsigned short x_tile[16][520];
    __shared__ __align__(16) unsigned short hA[16][520];    // h0_{i-1}
    __shared__ __align__(16) unsigned short hB[16][520];    // h1_{i-2}
    __shared__ float proj[3][16][17];                       // reused per half

    for (int i = tid; i < 16*520; i += NT) {
        ((unsigned short*)x_tile)[i] = 0;
        ((unsigned short*)hA)[i] = 0;
        ((unsigned short*)hB)[i] = 0;
    }
    __syncthreads();   // zero-init visible before staging

    const int lrow = lane & 15;
    const int lk   = (lane >> 4) << 3;

    // ---- weights for both layers in regs (gate waves only) ----
    short8 wf0[16], rf0[16], wf1[16], rf1[16];
    float bias0 = 0.f, bias1 = 0.f;
    if (wid < 3) {
        const int wrow = wid*HID + col0 + lrow;
#pragma unroll
        for (int kc = 0; kc < 16; ++kc) {
            wf0[kc] = load_frag(W + (size_t)wrow*HID + kc*32 + lk);
            rf0[kc] = load_frag(R + (size_t)wrow*HID + kc*32 + lk);
            wf1[kc] = load_frag(W + ((size_t)GATE + wrow)*HID + kc*32 + lk);
            rf1[kc] = load_frag(R + ((size_t)GATE + wrow)*HID + kc*32 + lk);
        }
        bias0 = bi[wrow] + bh[wrow];
        bias1 = bi[GATE + wrow] + bh[GATE + wrow];
    }

    // ---- state: 1 cell per thread ----
    const int lyr  = tid >> 7;            // waves 0,1 -> L0; waves 2,3 -> L1
    const int srow = (tid >> 4) & 7;
    const int scol = tid & 15;
    const float fgv = sigmoidf_(fw[(size_t)lyr*HID + col0 + scol]);
    float creg = c0[((size_t)lyr*BATCH + g*GROWS + srow)*HID + col0 + scol];

    // ---- prologue: stage x_0 and h0 tiles ----
    {
        const unsigned short* xp = xb + (size_t)g*GROWS*HID;
        for (int w = tid; w < GROWS*HID/8; w += NT) {
            const int r = w >> 6, c8 = (w & 63) << 3;
            *(short8*)(&x_tile[r][c8]) = *(const short8*)(xp + (size_t)r*HID + c8);
        }
        const float* hp0 = h0 + (size_t)g*GROWS*HID;
        const float* hp1 = h0 + ((size_t)BATCH + g*GROWS)*HID;
        for (int w = tid; w < GROWS*HID/4; w += NT) {
            const int r = w >> 7, c4 = (w & 127) << 2;
            floatx4 va_ = *(const floatx4*)(hp0 + (size_t)r*HID + c4);
            floatx4 vb_ = *(const floatx4*)(hp1 + (size_t)r*HID + c4);
            short4v pa, pb;
#pragma unroll
            for (int j = 0; j < 4; ++j) { pa[j] = (short)f2bf(va_[j]); pb[j] = (short)f2bf(vb_[j]); }
            *(short4v*)(&hA[r][c4]) = pa;
            *(short4v*)(&hB[r][c4]) = pb;
        }
    }
    __syncthreads();

    int budget = 1 << 22;
    int pend_t = -1;
    float pend_h = 0.f, pend_c = 0.f;
    u64 va0[8], va1[8];
    short8 xr0, xr1;

    for (int i = 0; i <= TSTEPS; ++i) {
        // ==== C0: consume h0_{i-1} (published mid-round i-1) ====
        if (i >= 1) {
            const unsigned want = (unsigned)i;
            const u64* rb0 = ring + ((size_t)((i - 1) & 3)*8 + g)*2048;
            unsigned stale = 0;
#pragma unroll
            for (int k = 0; k < 8; ++k)
                if ((unsigned)(va0[k] >> 32) != want) stale |= (1u << k);
            int pass = 0;
            while (__any((int)(stale != 0)) && budget > 0) {
                if (pass++) __builtin_amdgcn_s_sleep(1);
#pragma unroll
                for (int k = 0; k < 8; ++k)
                    if (stale & (1u << k)) va0[k] = ring_ld(rb0 + tid + (k << 8));
#pragma unroll
                for (int k = 0; k < 8; ++k)
                    if (stale & (1u << k))
                        if ((unsigned)(va0[k] >> 32) == want) stale &= ~(1u << k);
                --budget;
            }
#pragma unroll
            for (int k = 0; k < 8; ++k) {
                const int w = tid + (k << 8);
                const int b = w >> 6, r = (w >> 3) & 7, u = w & 7;
                *(unsigned*)(&hA[r][b*16 + u*2]) = (unsigned)va0[k];
            }
            if (i < TSTEPS) {   // xr holds x_i (issued at B4-end of round i-1)
                *(short8*)(&x_tile[tid >> 6][(tid & 63) << 3]) = xr0;
                const int w1 = tid + 256;
                *(short8*)(&x_tile[w1 >> 6][(w1 & 63) << 3]) = xr1;
            }
        }
        __syncthreads();   // B1

        // ==== L0 half: a0a + a0b + proj0 ====
        if (wid < 3 && i < TSTEPS) {
            floatx4 a0a = {0,0,0,0}, a0b = {0,0,0,0};
#pragma unroll
            for (int kc = 0; kc < 16; ++kc) {
                short8 afx = *(const short8*)(&x_tile[lrow][kc*32 + lk]);
                short8 afh = *(const short8*)(&hA[lrow][kc*32 + lk]);
                a0a = __builtin_amdgcn_mfma_f32_16x16x32_bf16(afx, wf0[kc], a0a, 0, 0, 0);
                a0b = __builtin_amdgcn_mfma_f32_16x16x32_bf16(afh, rf0[kc], a0b, 0, 0, 0);
            }
            const int erow0 = (lane >> 4) << 2, ecol = lrow;
#pragma unroll
            for (int q = 0; q < 4; ++q)
                proj[wid][erow0 + q][ecol] = sigmoidf_(a0a[q] + a0b[q] + bias0);
        }
        __syncthreads();   // B2

        // ==== issue va1 sweep (h1_{i-2}) BEFORE any publish this half ====
        if (i >= 2) {
            const u64* rb1 = ring + ((size_t)(4 + ((i - 2) & 3))*8 + g)*2048;
#pragma unroll
            for (int k = 0; k < 8; ++k)
                va1[k] = ring_ld(rb1 + tid + (k << 8));
        }
        __builtin_amdgcn_sched_barrier(0);

        // ==== E0: flush deferred outs; L0 state update + publish h0_i ====
        if (pend_t >= 0) {
            if (lyr == 1)
                out[((size_t)pend_t*BATCH + g*GROWS + srow)*HID + col0 + scol] = pend_h;
            if (pend_t == TSTEPS - 1) {
                const size_t fo = (size_t)TSTEPS*BATCH*HID
                                + ((size_t)lyr*BATCH + g*GROWS + srow)*HID + col0 + scol;
                out[fo] = pend_h;
                out[fo + (size_t)2*BATCH*HID] = pend_c;
            }
            pend_t = -1;
        }
        if (lyr == 0 && i < TSTEPS) {
            const float ig = proj[0][srow][scol];
            const float og = proj[1][srow][scol];
            const float zz = proj[2][srow][scol];
            const float c_ = creg*fgv + zz - ig;
            creg = c_;
            const float h_ = sigmoidf_(c_) - og;
            const unsigned hu = __float_as_uint(h_);
            const unsigned pu = (unsigned)__builtin_amdgcn_ds_swizzle((int)hu, 0x041F);
            unsigned pay;
            asm volatile("v_cvt_pk_bf16_f32 %0, %1, %2"
                         : "=v"(pay) : "v"(h_), "v"(__uint_as_float(pu)));
            if (!(scol & 1)) {
                const size_t off = (((size_t)(i & 3)*8 + g)*32 + bidx)*64
                                 + srow*8 + (scol >> 1);
                ring_st(ring + off, (u64)pay | ((u64)(unsigned)(i + 1) << 32));
            }
            if (i == TSTEPS - 1) { pend_t = i; pend_h = h_; pend_c = c_; }  // finals
        }
        __builtin_amdgcn_sched_barrier(0);

        // ==== a1a = hA @ W1 (flight cover for va1) ====
        floatx4 a1a = {0,0,0,0};
        if (wid < 3 && i >= 1) {
#pragma unroll
            for (int kc = 0; kc < 16; ++kc) {
                short8 afh = *(const short8*)(&hA[lrow][kc*32 + lk]);
                a1a = __builtin_amdgcn_mfma_f32_16x16x32_bf16(afh, wf1[kc], a1a, 0, 0, 0);
            }
        }
        __builtin_amdgcn_sched_barrier(0);

        // ==== C1: consume h1_{i-2} (published round i-1) ====
        if (i >= 2) {
            const unsigned want = (unsigned)(i - 1);
            const u64* rb1 = ring + ((size_t)(4 + ((i - 2) & 3))*8 + g)*2048;
            unsigned stale = 0;
#pragma unroll
            for (int k = 0; k < 8; ++k)
                if ((unsigned)(va1[k] >> 32) != want) stale |= (1u << k);
            int pass = 0;
            while (__any((int)(stale != 0)) && budget > 0) {
                if (pass++) __builtin_amdgcn_s_sleep(1);
#pragma unroll
                for (int k = 0; k < 8; ++k)
                    if (stale & (1u << k)) va1[k] = ring_ld(rb1 + tid + (k << 8));
#pragma unroll
                for (int k = 0; k < 8; ++k)
                    if (stale & (1u << k))
                        if ((unsigned)(va1[k] >> 32) == want) stale &= ~(1u << k);
                --budget;
            }
#pragma unroll
            for (int k = 0; k < 8; ++k) {
                const int w = tid + (k << 8);
                const int b = w >> 6, r = (w >> 3) & 7, u = w & 7;
                *(unsigned*)(&hB[r][b*16 + u*2]) = (unsigned)va1[k];
            }
        }
        __syncthreads();   // B3

        // ==== L1 half: a1b + proj1 ====
        if (wid < 3 && i >= 1) {
            floatx4 a1b = {0,0,0,0};
#pragma unroll
            for (int kc = 0; kc < 16; ++kc) {
                short8 afb = *(const short8*)(&hB[lrow][kc*32 + lk]);
                a1b = __builtin_amdgcn_mfma_f32_16x16x32_bf16(afb, rf1[kc], a1b, 0, 0, 0);
            }
            const int erow0 = (lane >> 4) << 2, ecol = lrow;
#pragma unroll
            for (int q = 0; q < 4; ++q)
                proj[wid][erow0 + q][ecol] = sigmoidf_(a1a[q] + a1b[q] + bias1);
        }
        __syncthreads();   // B4

        // ==== issue va0 sweep (h0_i, published at E0 above) + x prefetch ====
        if (i < TSTEPS) {
            const u64* rb0n = ring + ((size_t)(i & 3)*8 + g)*2048;
#pragma unroll
            for (int k = 0; k < 8; ++k)
                va0[k] = ring_ld(rb0n + tid + (k << 8));
        }
        if (i + 1 < TSTEPS) {
            const unsigned short* xp = xb + ((size_t)(i + 1)*BATCH + g*GROWS)*HID;
            xr0 = *(const short8*)(xp + (size_t)(tid >> 6)*HID + ((tid & 63) << 3));
            const int w1 = tid + 256;
            xr1 = *(const short8*)(xp + (size_t)(w1 >> 6)*HID + ((w1 & 63) << 3));
        }
        __builtin_amdgcn_sched_barrier(0);

        // ==== E1: L1 state update + publish h1_{i-1}; defer out stores ====
        if (lyr == 1 && i >= 1) {
            const int t = i - 1;
            const float ig = proj[0][srow][scol];
            const float og = proj[1][srow][scol];
            const float zz = proj[2][srow][scol];
            const float c_ = creg*fgv + zz - ig;
            creg = c_;
            const float h_ = sigmoidf_(c_) - og;
            const unsigned hu = __float_as_uint(h_);
            const unsigned pu = (unsigned)__builtin_amdgcn_ds_swizzle((int)hu, 0x041F);
            unsigned pay;
            asm volatile("v_cvt_pk_bf16_f32 %0, %1, %2"
                         : "=v"(pay) : "v"(h_), "v"(__uint_as_float(pu)));
            if (!(scol & 1)) {
                const size_t off = (((size_t)(4 + (t & 3))*8 + g)*32 + bidx)*64
                                 + srow*8 + (scol >> 1);
                ring_st(ring + off, (u64)pay | ((u64)(unsigned)(t + 1) << 32));
            }
            pend_t = t; pend_h = h_; pend_c = c_;
        }
    }

    // ---- post-loop: flush the last deferred stores ----
    if (pend_t >= 0) {
        if (lyr == 1)
            out[((size_t)pend_t*BATCH + g*GROWS + srow)*HID + col0 + scol] = pend_h;
        if (pend_t == TSTEPS - 1) {
            const size_t fo = (size_t)TSTEPS*BATCH*HID
                            + ((size_t)lyr*BATCH + g*GROWS + srow)*HID + col0 + scol;
            out[fo] = pend_h;
            out[fo + (size_t)2*BATCH*HID] = pend_c;
        }
    }
}

extern "C" void kernel_launch(void* const* d_in, const int* in_sizes, int n_in,
                              void* d_out, int out_size, void* d_ws, size_t ws_size,
                              hipStream_t stream)
{
    (void)in_sizes; (void)n_in; (void)out_size; (void)ws_size;
    const float* x  = (const float*)d_in[0];
    const float* h0 = (const float*)d_in[1];
    const float* c0 = (const float*)d_in[2];
    const float* W  = (const float*)d_in[3];
    const float* R  = (const float*)d_in[4];
    const float* bi = (const float*)d_in[5];
    const float* bh = (const float*)d_in[6];
    const float* fw = (const float*)d_in[7];
    float* out = (float*)d_out;

    u64* ring = (u64*)d_ws;                                             // 1 MB
    unsigned short* xbuf = (unsigned short*)((char*)d_ws + (2u << 20)); // 64 MB

    hipMemsetAsync(d_ws, 0, (size_t)2*4*8*2048*8, stream);  // hygiene

    xconvert<<<dim3(TSTEPS*BATCH*HID/(256*8)), dim3(256), 0, stream>>>(x, xbuf);

    sublstm_fused<<<dim3(NBLOCKS), dim3(NT), 0, stream>>>(
        xbuf, W, R, bi, bh, fw, h0, c0, ring, out);
}

// Round 12
// 3390.788 us; speedup vs baseline: 1.5081x; 1.0226x over previous
//
#include <hip/hip_runtime.h>
#include <hip/hip_bf16.h>
#include <stdint.h>

// SubLSTM T=1024, B=64, H=512, GATE=3H, L=2 — fused 2-layer pipelined,
// round 12: r11 staggered rounds + drain-safe vmem issue homes.
// In-order vmcnt retirement means a retry's wait drains ALL older in-flight
// vmem. r11 exposed retries to the x HBM prefetch (C0) and out-store acks
// (C1). Now: x prefetch issues at C0-end (full round to drain); out-flush
// moves to after C1's stash; va0 sweep issues before B4 (more flight).
//
// Round i:  C0{check va0 -> hA, stash xr} -> issue xr' -> B1
//        -> L0 (a0a,a0b,proj0) -> B2 -> issue va1 -> E0 (publish h0_i)
//        -> a1a (cover) -> C1{check va1 -> hB} -> flush outs -> B3
//        -> L1 (a1b,proj1) -> issue va0' -> B4 -> E1 (publish h1_{i-1})
// Protocol: u64 = (tag32<<32)|(2xbf16), relaxed agent atomics (data IS the
// flag; single-copy atomic). Ring depth 4; lock-step bounds skew <=3 (audited:
// block at E0_{i+4} implies all blocks passed C0_{i+3}); cross-replay stale
// accepts are bit-identical; 0xAA poison never matches a wanted tag.

#define TSTEPS 1024
#define BATCH  64
#define HID    512
#define GATE   1536
#define GROWS  8
#define NT     256
#define NBLOCKS 256

typedef unsigned long long u64;
typedef __attribute__((ext_vector_type(8))) short short8;
typedef __attribute__((ext_vector_type(4))) short short4v;
typedef __attribute__((ext_vector_type(4))) float floatx4;

__device__ __forceinline__ float sigmoidf_(float x) { return 1.0f / (1.0f + __expf(-x)); }

__device__ __forceinline__ unsigned short f2bf(float x) {
    union { float f; unsigned u; } v; v.f = x;
    unsigned r = v.u + 0x7FFFu + ((v.u >> 16) & 1u);   // RNE
    return (unsigned short)(r >> 16);
}

__device__ __forceinline__ short8 load_frag(const float* p) {
    floatx4 a = *(const floatx4*)p;
    floatx4 b = *(const floatx4*)(p + 4);
    short8 r;
#pragma unroll
    for (int j = 0; j < 4; ++j) { r[j] = (short)f2bf(a[j]); r[j+4] = (short)f2bf(b[j]); }
    return r;
}

__device__ __forceinline__ u64 ring_ld(const u64* p) {
    return __hip_atomic_load(p, __ATOMIC_RELAXED, __HIP_MEMORY_SCOPE_AGENT);
}
__device__ __forceinline__ void ring_st(u64* p, u64 v) {
    __hip_atomic_store(p, v, __ATOMIC_RELAXED, __HIP_MEMORY_SCOPE_AGENT);
}

// ---- preamble: x f32 -> bf16 ----
__global__ __launch_bounds__(256) void xconvert(const float* __restrict__ x,
                                                unsigned short* __restrict__ xb) {
    const size_t i = ((size_t)blockIdx.x*256 + threadIdx.x) * 8;
    floatx4 a = *(const floatx4*)(x + i);
    floatx4 b = *(const floatx4*)(x + i + 4);
    short8 p;
#pragma unroll
    for (int j = 0; j < 4; ++j) { p[j] = (short)f2bf(a[j]); p[j+4] = (short)f2bf(b[j]); }
    *(short8*)(xb + i) = p;
}

__global__ __launch_bounds__(NT, 1) void sublstm_fused(
    const unsigned short* __restrict__ xb,
    const float* __restrict__ W,
    const float* __restrict__ R,
    const float* __restrict__ bi,
    const float* __restrict__ bh,
    const float* __restrict__ fw,
    const float* __restrict__ h0,
    const float* __restrict__ c0,
    u64* __restrict__ ring,        // [lyr 2][slot 4][grp 8][blk 32][row 8][unit 8]
    float* __restrict__ out)
{
    const int tid  = threadIdx.x;
    const int lane = tid & 63;
    const int wid  = tid >> 6;            // 0,1,2 = i/o/z gate waves; 3 = helper
    const int bid  = blockIdx.x;
    const int g    = bid & 7;             // batch group
    const int bidx = bid >> 3;            // 0..31: 16-col slice
    const int col0 = bidx << 4;

    __shared__ __align__(16) unsigned short x_tile[16][520];
    __shared__ __align__(16) unsigned short hA[16][520];    // h0_{i-1}
    __shared__ __align__(16) unsigned short hB[16][520];    // h1_{i-2}
    __shared__ float proj[3][16][17];                       // reused per half

    for (int i = tid; i < 16*520; i += NT) {
        ((unsigned short*)x_tile)[i] = 0;
        ((unsigned short*)hA)[i] = 0;
        ((unsigned short*)hB)[i] = 0;
    }
    __syncthreads();   // zero-init visible before staging

    const int lrow = lane & 15;
    const int lk   = (lane >> 4) << 3;

    // ---- weights for both layers in regs (gate waves only) ----
    short8 wf0[16], rf0[16], wf1[16], rf1[16];
    float bias0 = 0.f, bias1 = 0.f;
    if (wid < 3) {
        const int wrow = wid*HID + col0 + lrow;
#pragma unroll
        for (int kc = 0; kc < 16; ++kc) {
            wf0[kc] = load_frag(W + (size_t)wrow*HID + kc*32 + lk);
            rf0[kc] = load_frag(R + (size_t)wrow*HID + kc*32 + lk);
            wf1[kc] = load_frag(W + ((size_t)GATE + wrow)*HID + kc*32 + lk);
            rf1[kc] = load_frag(R + ((size_t)GATE + wrow)*HID + kc*32 + lk);
        }
        bias0 = bi[wrow] + bh[wrow];
        bias1 = bi[GATE + wrow] + bh[GATE + wrow];
    }

    // ---- state: 1 cell per thread ----
    const int lyr  = tid >> 7;            // waves 0,1 -> L0; waves 2,3 -> L1
    const int srow = (tid >> 4) & 7;
    const int scol = tid & 15;
    const float fgv = sigmoidf_(fw[(size_t)lyr*HID + col0 + scol]);
    float creg = c0[((size_t)lyr*BATCH + g*GROWS + srow)*HID + col0 + scol];

    // ---- prologue: stage x_0 and h0 tiles ----
    {
        const unsigned short* xp = xb + (size_t)g*GROWS*HID;
        for (int w = tid; w < GROWS*HID/8; w += NT) {
            const int r = w >> 6, c8 = (w & 63) << 3;
            *(short8*)(&x_tile[r][c8]) = *(const short8*)(xp + (size_t)r*HID + c8);
        }
        const float* hp0 = h0 + (size_t)g*GROWS*HID;
        const float* hp1 = h0 + ((size_t)BATCH + g*GROWS)*HID;
        for (int w = tid; w < GROWS*HID/4; w += NT) {
            const int r = w >> 7, c4 = (w & 127) << 2;
            floatx4 va_ = *(const floatx4*)(hp0 + (size_t)r*HID + c4);
            floatx4 vb_ = *(const floatx4*)(hp1 + (size_t)r*HID + c4);
            short4v pa, pb;
#pragma unroll
            for (int j = 0; j < 4; ++j) { pa[j] = (short)f2bf(va_[j]); pb[j] = (short)f2bf(vb_[j]); }
            *(short4v*)(&hA[r][c4]) = pa;
            *(short4v*)(&hB[r][c4]) = pb;
        }
    }
    __syncthreads();

    int budget = 1 << 22;
    int pend_t = -1;
    float pend_h = 0.f, pend_c = 0.f;
    u64 va0[8], va1[8];
    short8 xr0, xr1;

    for (int i = 0; i <= TSTEPS; ++i) {
        // ==== C0: consume h0_{i-1}; stash xr (x_i, ~3us old, drained) ====
        if (i >= 1) {
            const unsigned want = (unsigned)i;
            const u64* rb0 = ring + ((size_t)((i - 1) & 3)*8 + g)*2048;
            unsigned stale = 0;
#pragma unroll
            for (int k = 0; k < 8; ++k)
                if ((unsigned)(va0[k] >> 32) != want) stale |= (1u << k);
            int pass = 0;
            while (__any((int)(stale != 0)) && budget > 0) {
                if (pass++) __builtin_amdgcn_s_sleep(1);
#pragma unroll
                for (int k = 0; k < 8; ++k)
                    if (stale & (1u << k)) va0[k] = ring_ld(rb0 + tid + (k << 8));
#pragma unroll
                for (int k = 0; k < 8; ++k)
                    if (stale & (1u << k))
                        if ((unsigned)(va0[k] >> 32) == want) stale &= ~(1u << k);
                --budget;
            }
#pragma unroll
            for (int k = 0; k < 8; ++k) {
                const int w = tid + (k << 8);
                const int b = w >> 6, r = (w >> 3) & 7, u = w & 7;
                *(unsigned*)(&hA[r][b*16 + u*2]) = (unsigned)va0[k];
            }
            if (i < TSTEPS) {
                *(short8*)(&x_tile[tid >> 6][(tid & 63) << 3]) = xr0;
                const int w1 = tid + 256;
                *(short8*)(&x_tile[w1 >> 6][(w1 & 63) << 3]) = xr1;
            }
        }
        // issue xr' <- x_{i+1}: full round to drain before anything waits on it
        if (i + 1 < TSTEPS) {
            const unsigned short* xp = xb + ((size_t)(i + 1)*BATCH + g*GROWS)*HID;
            xr0 = *(const short8*)(xp + (size_t)(tid >> 6)*HID + ((tid & 63) << 3));
            const int w1 = tid + 256;
            xr1 = *(const short8*)(xp + (size_t)(w1 >> 6)*HID + ((w1 & 63) << 3));
        }
        __syncthreads();   // B1

        // ==== L0 half: a0a + a0b + proj0 ====
        if (wid < 3 && i < TSTEPS) {
            floatx4 a0a = {0,0,0,0}, a0b = {0,0,0,0};
#pragma unroll
            for (int kc = 0; kc < 16; ++kc) {
                short8 afx = *(const short8*)(&x_tile[lrow][kc*32 + lk]);
                short8 afh = *(const short8*)(&hA[lrow][kc*32 + lk]);
                a0a = __builtin_amdgcn_mfma_f32_16x16x32_bf16(afx, wf0[kc], a0a, 0, 0, 0);
                a0b = __builtin_amdgcn_mfma_f32_16x16x32_bf16(afh, rf0[kc], a0b, 0, 0, 0);
            }
            const int erow0 = (lane >> 4) << 2, ecol = lrow;
#pragma unroll
            for (int q = 0; q < 4; ++q)
                proj[wid][erow0 + q][ecol] = sigmoidf_(a0a[q] + a0b[q] + bias0);
        }
        __syncthreads();   // B2

        // ==== issue va1 sweep (h1_{i-2}, publ. E1 round i-1) ====
        if (i >= 2) {
            const u64* rb1 = ring + ((size_t)(4 + ((i - 2) & 3))*8 + g)*2048;
#pragma unroll
            for (int k = 0; k < 8; ++k)
                va1[k] = ring_ld(rb1 + tid + (k << 8));
        }
        __builtin_amdgcn_sched_barrier(0);

        // ==== E0: L0 state update + publish h0_i (no out-flush here) ====
        if (lyr == 0 && i < TSTEPS) {
            const float ig = proj[0][srow][scol];
            const float og = proj[1][srow][scol];
            const float zz = proj[2][srow][scol];
            const float c_ = creg*fgv + zz - ig;
            creg = c_;
            const float h_ = sigmoidf_(c_) - og;
            const unsigned hu = __float_as_uint(h_);
            const unsigned pu = (unsigned)__builtin_amdgcn_ds_swizzle((int)hu, 0x041F);
            unsigned pay;
            asm volatile("v_cvt_pk_bf16_f32 %0, %1, %2"
                         : "=v"(pay) : "v"(h_), "v"(__uint_as_float(pu)));
            if (!(scol & 1)) {
                const size_t off = (((size_t)(i & 3)*8 + g)*32 + bidx)*64
                                 + srow*8 + (scol >> 1);
                ring_st(ring + off, (u64)pay | ((u64)(unsigned)(i + 1) << 32));
            }
            if (i == TSTEPS - 1) { pend_t = i; pend_h = h_; pend_c = c_; }  // finals
        }
        __builtin_amdgcn_sched_barrier(0);

        // ==== a1a = hA @ W1 (flight cover for va1) ====
        floatx4 a1a = {0,0,0,0};
        if (wid < 3 && i >= 1) {
#pragma unroll
            for (int kc = 0; kc < 16; ++kc) {
                short8 afh = *(const short8*)(&hA[lrow][kc*32 + lk]);
                a1a = __builtin_amdgcn_mfma_f32_16x16x32_bf16(afh, wf1[kc], a1a, 0, 0, 0);
            }
        }
        __builtin_amdgcn_sched_barrier(0);

        // ==== C1: consume h1_{i-2} ====
        if (i >= 2) {
            const unsigned want = (unsigned)(i - 1);
            const u64* rb1 = ring + ((size_t)(4 + ((i - 2) & 3))*8 + g)*2048;
            unsigned stale = 0;
#pragma unroll
            for (int k = 0; k < 8; ++k)
                if ((unsigned)(va1[k] >> 32) != want) stale |= (1u << k);
            int pass = 0;
            while (__any((int)(stale != 0)) && budget > 0) {
                if (pass++) __builtin_amdgcn_s_sleep(1);
#pragma unroll
                for (int k = 0; k < 8; ++k)
                    if (stale & (1u << k)) va1[k] = ring_ld(rb1 + tid + (k << 8));
#pragma unroll
                for (int k = 0; k < 8; ++k)
                    if (stale & (1u << k))
                        if ((unsigned)(va1[k] >> 32) == want) stale &= ~(1u << k);
                --budget;
            }
#pragma unroll
            for (int k = 0; k < 8; ++k) {
                const int w = tid + (k << 8);
                const int b = w >> 6, r = (w >> 3) & 7, u = w & 7;
                *(unsigned*)(&hB[r][b*16 + u*2]) = (unsigned)va1[k];
            }
        }
        // ==== flush deferred outs (youngest now; drains under L1+E1+next C0) ====
        if (pend_t >= 0 && !(lyr == 0 && pend_t == TSTEPS - 1 && i == TSTEPS - 1 && false)) {
            if (lyr == 1)
                out[((size_t)pend_t*BATCH + g*GROWS + srow)*HID + col0 + scol] = pend_h;
            if (pend_t == TSTEPS - 1) {
                const size_t fo = (size_t)TSTEPS*BATCH*HID
                                + ((size_t)lyr*BATCH + g*GROWS + srow)*HID + col0 + scol;
                out[fo] = pend_h;
                out[fo + (size_t)2*BATCH*HID] = pend_c;
            }
            pend_t = -1;
        }
        __syncthreads();   // B3

        // ==== L1 half: a1b + proj1 ====
        if (wid < 3 && i >= 1) {
            floatx4 a1b = {0,0,0,0};
#pragma unroll
            for (int kc = 0; kc < 16; ++kc) {
                short8 afb = *(const short8*)(&hB[lrow][kc*32 + lk]);
                a1b = __builtin_amdgcn_mfma_f32_16x16x32_bf16(afb, rf1[kc], a1b, 0, 0, 0);
            }
            const int erow0 = (lane >> 4) << 2, ecol = lrow;
#pragma unroll
            for (int q = 0; q < 4; ++q)
                proj[wid][erow0 + q][ecol] = sigmoidf_(a1a[q] + a1b[q] + bias1);
        }
        // ==== issue va0' (h0_i, publ. E0 this round ~1us ago) ====
        if (i < TSTEPS) {
            const u64* rb0n = ring + ((size_t)(i & 3)*8 + g)*2048;
#pragma unroll
            for (int k = 0; k < 8; ++k)
                va0[k] = ring_ld(rb0n + tid + (k << 8));
        }
        __syncthreads();   // B4

        // ==== E1: L1 state update + publish h1_{i-1}; defer out stores ====
        if (lyr == 1 && i >= 1) {
            const int t = i - 1;
            const float ig = proj[0][srow][scol];
            const float og = proj[1][srow][scol];
            const float zz = proj[2][srow][scol];
            const float c_ = creg*fgv + zz - ig;
            creg = c_;
            const float h_ = sigmoidf_(c_) - og;
            const unsigned hu = __float_as_uint(h_);
            const unsigned pu = (unsigned)__builtin_amdgcn_ds_swizzle((int)hu, 0x041F);
            unsigned pay;
            asm volatile("v_cvt_pk_bf16_f32 %0, %1, %2"
                         : "=v"(pay) : "v"(h_), "v"(__uint_as_float(pu)));
            if (!(scol & 1)) {
                const size_t off = (((size_t)(4 + (t & 3))*8 + g)*32 + bidx)*64
                                 + srow*8 + (scol >> 1);
                ring_st(ring + off, (u64)pay | ((u64)(unsigned)(t + 1) << 32));
            }
            pend_t = t; pend_h = h_; pend_c = c_;
        }
    }

    // ---- post-loop: flush the last deferred stores ----
    if (pend_t >= 0) {
        if (lyr == 1)
            out[((size_t)pend_t*BATCH + g*GROWS + srow)*HID + col0 + scol] = pend_h;
        if (pend_t == TSTEPS - 1) {
            const size_t fo = (size_t)TSTEPS*BATCH*HID
                            + ((size_t)lyr*BATCH + g*GROWS + srow)*HID + col0 + scol;
            out[fo] = pend_h;
            out[fo + (size_t)2*BATCH*HID] = pend_c;
        }
    }
}

extern "C" void kernel_launch(void* const* d_in, const int* in_sizes, int n_in,
                              void* d_out, int out_size, void* d_ws, size_t ws_size,
                              hipStream_t stream)
{
    (void)in_sizes; (void)n_in; (void)out_size; (void)ws_size;
    const float* x  = (const float*)d_in[0];
    const float* h0 = (const float*)d_in[1];
    const float* c0 = (const float*)d_in[2];
    const float* W  = (const float*)d_in[3];
    const float* R  = (const float*)d_in[4];
    const float* bi = (const float*)d_in[5];
    const float* bh = (const float*)d_in[6];
    const float* fw = (const float*)d_in[7];
    float* out = (float*)d_out;

    u64* ring = (u64*)d_ws;                                             // 1 MB
    unsigned short* xbuf = (unsigned short*)((char*)d_ws + (2u << 20)); // 64 MB

    hipMemsetAsync(d_ws, 0, (size_t)2*4*8*2048*8, stream);  // hygiene

    xconvert<<<dim3(TSTEPS*BATCH*HID/(256*8)), dim3(256), 0, stream>>>(x, xbuf);

    sublstm_fused<<<dim3(NBLOCKS), dim3(NT), 0, stream>>>(
        xbuf, W, R, bi, bh, fw, h0, c0, ring, out);
}